// Round 1
// baseline (441.089 us; speedup 1.0000x reference)
//
#include <hip/hip_runtime.h>
#include <math.h>

// DigitCaps dynamic routing, MI355X.
// Shapes: u[B=128, R=864, I=4] f32, W[1, J=166, R=864, O=8, I=4] f32.
// Out: v[B=128, J=166, O=8] f32.
//
// Design (round 0): one wave (64 lanes) per (b,j) pair. Lane l owns routes
// r = l + 64*k, k in [0,14) (lanes 0..31 have 14 routes, 32..63 have 13).
// u_hat[r,o] lives entirely in registers (14*8 = 112 VGPRs/lane). All
// routing reductions (sum over r, max over r, squash) are 64-lane shuffle
// butterflies — no LDS, no barriers. W[j] is streamed from L2/LLC once per
// (b,j); consecutive waves share j for cache locality.

#define BB 128
#define JJ 166
#define RR 864
#define OO 8
#define KMAX 14           // ceil(864/64); lane<32 -> 14 routes, else 13
#define WAVES_PER_BLOCK 4

__device__ __forceinline__ float wave_sum(float v) {
#pragma unroll
    for (int m = 32; m >= 1; m >>= 1) v += __shfl_xor(v, m, 64);
    return v;
}

__device__ __forceinline__ float wave_max(float v) {
#pragma unroll
    for (int m = 32; m >= 1; m >>= 1) v = fmaxf(v, __shfl_xor(v, m, 64));
    return v;
}

__global__ __launch_bounds__(WAVES_PER_BLOCK * 64) void digitcaps_kernel(
    const float* __restrict__ u, const float* __restrict__ W,
    float* __restrict__ out) {
    const int tid = threadIdx.x;
    const int lane = tid & 63;
    const int wid = blockIdx.x * WAVES_PER_BLOCK + (tid >> 6);
    // b minor so the 4 waves of a block (and neighboring blocks) share j -> W[j] L1/L2 reuse
    const int j = wid >> 7;   // wid / 128
    const int b = wid & 127;  // wid % 128

    const float4* __restrict__ u4 = (const float4*)u;  // [B][R]
    const float4* __restrict__ W4 = (const float4*)W;  // [J][R][O]

    // ---- compute u_hat into registers ----
    float uhat[KMAX][OO];
#pragma unroll
    for (int k = 0; k < KMAX; ++k) {
        const int r = lane + 64 * k;
        const bool valid = (k < KMAX - 1) || (lane < (RR - 64 * (KMAX - 1)));
        if (valid) {
            const float4 uu = u4[b * RR + r];
#pragma unroll
            for (int o = 0; o < OO; ++o) {
                const float4 ww = W4[(j * RR + r) * OO + o];
                uhat[k][o] = ww.x * uu.x + ww.y * uu.y + ww.z * uu.z + ww.w * uu.w;
            }
        } else {
#pragma unroll
            for (int o = 0; o < OO; ++o) uhat[k][o] = 0.0f;
        }
    }

    float b_r[KMAX];
#pragma unroll
    for (int k = 0; k < KMAX; ++k) b_r[k] = 0.0f;

    float v[OO];

    // ---- iteration 0: b=0 -> c uniform = 1/R ----
    {
        float s[OO];
#pragma unroll
        for (int o = 0; o < OO; ++o) {
            float p = 0.0f;
#pragma unroll
            for (int k = 0; k < KMAX; ++k) p += uhat[k][o];
            s[o] = wave_sum(p) * (1.0f / (float)RR);
        }
        float n2 = 0.0f;
#pragma unroll
        for (int o = 0; o < OO; ++o) n2 += s[o] * s[o];
        const float scale = sqrtf(n2) / (1.0f + n2);
#pragma unroll
        for (int o = 0; o < OO; ++o) v[o] = s[o] * scale;
        // b_ij += <uhat, v>   (b was 0)
#pragma unroll
        for (int k = 0; k < KMAX; ++k) {
            float a = 0.0f;
#pragma unroll
            for (int o = 0; o < OO; ++o) a += uhat[k][o] * v[o];
            b_r[k] = a;
        }
    }

    // ---- iterations 1 and 2 ----
#pragma unroll
    for (int it = 1; it < 3; ++it) {
        // softmax over r of b_r
        float mloc = -INFINITY;
#pragma unroll
        for (int k = 0; k < KMAX; ++k) {
            const bool valid = (k < KMAX - 1) || (lane < (RR - 64 * (KMAX - 1)));
            if (valid) mloc = fmaxf(mloc, b_r[k]);
        }
        const float m = wave_max(mloc);

        float zp = 0.0f;
        float sp[OO];
#pragma unroll
        for (int o = 0; o < OO; ++o) sp[o] = 0.0f;
#pragma unroll
        for (int k = 0; k < KMAX; ++k) {
            const bool valid = (k < KMAX - 1) || (lane < (RR - 64 * (KMAX - 1)));
            const float e = valid ? __expf(b_r[k] - m) : 0.0f;
            zp += e;
#pragma unroll
            for (int o = 0; o < OO; ++o) sp[o] += e * uhat[k][o];
        }
        const float Z = wave_sum(zp);
        const float invZ = 1.0f / Z;

        float s[OO];
#pragma unroll
        for (int o = 0; o < OO; ++o) s[o] = wave_sum(sp[o]) * invZ;

        float n2 = 0.0f;
#pragma unroll
        for (int o = 0; o < OO; ++o) n2 += s[o] * s[o];
        const float scale = sqrtf(n2) / (1.0f + n2);
#pragma unroll
        for (int o = 0; o < OO; ++o) v[o] = s[o] * scale;

        if (it < 2) {
#pragma unroll
            for (int k = 0; k < KMAX; ++k) {
                float a = 0.0f;
#pragma unroll
                for (int o = 0; o < OO; ++o) a += uhat[k][o] * v[o];
                b_r[k] += a;
            }
        }
    }

    // ---- write out[b][j][o]; all lanes hold v after butterfly reductions ----
    float outv = 0.0f;
#pragma unroll
    for (int o = 0; o < OO; ++o)
        if (lane == o) outv = v[o];
    if (lane < OO) out[(b * JJ + j) * OO + lane] = outv;
}

extern "C" void kernel_launch(void* const* d_in, const int* in_sizes, int n_in,
                              void* d_out, int out_size, void* d_ws, size_t ws_size,
                              hipStream_t stream) {
    const float* u = (const float*)d_in[0];  // [128, 864, 4]
    const float* W = (const float*)d_in[1];  // [1, 166, 864, 8, 4]
    float* out = (float*)d_out;              // [128, 166, 8]

    const int total_waves = BB * JJ;                          // 21248
    const int grid = total_waves / WAVES_PER_BLOCK;           // 5312
    digitcaps_kernel<<<grid, WAVES_PER_BLOCK * 64, 0, stream>>>(u, W, out);
}

// Round 2
// 259.081 us; speedup vs baseline: 1.7025x; 1.7025x over previous
//
#include <hip/hip_runtime.h>
#include <math.h>

// DigitCaps dynamic routing, MI355X. Round 1: LDS-staged W.
// Shapes: u[B=128, R=864, I=4] f32, W[1, J=166, R=864, O=8, I=4] f32.
// Out: v[B=128, J=166, O=8] f32.
//
// Block = 256 threads = 4 waves, all sharing one j, handling 4 consecutive b.
// W[j] (108 KB) is staged into LDS in 2 halves (57.4 KB, transposed layout
// wlds[o][r] with row stride 449 -> conflict-free ds_write_b128 AND
// ds_read_b128). Global W reads are fully coalesced and amortized 4x across
// the block's waves. uhat[r,o] lives in registers (lane owns r = lane+64k),
// routing reductions are 64-lane shuffle butterflies as in round 0.

#define BB 128
#define JJ 166
#define RR 864
#define OO 8
#define KMAX 14            // ceil(864/64); k=13 has only lanes 0..31 valid
#define RPAD 449           // LDS row stride in float4 (448 routes + 1 pad)

__device__ __forceinline__ float wave_sum(float v) {
#pragma unroll
    for (int m = 32; m >= 1; m >>= 1) v += __shfl_xor(v, m, 64);
    return v;
}

__device__ __forceinline__ float wave_max(float v) {
#pragma unroll
    for (int m = 32; m >= 1; m >>= 1) v = fmaxf(v, __shfl_xor(v, m, 64));
    return v;
}

__global__ __launch_bounds__(256) void digitcaps_kernel(
    const float* __restrict__ u, const float* __restrict__ W,
    float* __restrict__ out) {
    const int tid = threadIdx.x;
    const int lane = tid & 63;
    const int wave = tid >> 6;

    // 32 blocks per j (128 b / 4 per block); consecutive blocks share j.
    const int j = blockIdx.x >> 5;
    const int b = ((blockIdx.x & 31) << 2) + wave;

    const float4* __restrict__ u4 = (const float4*)u;  // [B][R]
    const float4* __restrict__ W4 = (const float4*)W;  // [J][R][O]

    __shared__ float4 wlds[OO * RPAD];  // 57,472 B

    float uhat[KMAX][OO];

    // ---- stage W[j] half-by-half; compute uhat into registers ----
#pragma unroll
    for (int h = 0; h < 2; ++h) {
        __syncthreads();  // protect LDS reuse across halves
        const int base = j * (RR * OO) + h * 3584;  // float4 index; 448*8=3584
        const int iters = h ? 13 : 14;              // 3328 / 3584 float4s, exact
#pragma unroll
        for (int i = 0; i < iters; ++i) {
            const int e = tid + (i << 8);
            const float4 w = W4[base + e];
            wlds[(e & 7) * RPAD + (e >> 3)] = w;  // transposed: [o][r_local]
        }
        __syncthreads();

        const int k0 = h * 7;
#pragma unroll
        for (int k = k0; k < k0 + 7; ++k) {
            const int r = lane + (k << 6);
            const bool valid = (k < KMAX - 1) || (lane < 32);
            if (valid) {
                const float4 uu = u4[b * RR + r];
                const int rl = r - h * 448;
#pragma unroll
                for (int o = 0; o < OO; ++o) {
                    const float4 ww = wlds[o * RPAD + rl];
                    uhat[k][o] = ww.x * uu.x + ww.y * uu.y + ww.z * uu.z + ww.w * uu.w;
                }
            } else {
#pragma unroll
                for (int o = 0; o < OO; ++o) uhat[k][o] = 0.0f;
            }
        }
    }

    // ---- routing (register + shuffle only) ----
    float b_r[KMAX];
#pragma unroll
    for (int k = 0; k < KMAX; ++k) b_r[k] = 0.0f;

    float v[OO];

    // iteration 0: b_ij = 0 -> c uniform = 1/R
    {
        float s[OO];
#pragma unroll
        for (int o = 0; o < OO; ++o) {
            float p = 0.0f;
#pragma unroll
            for (int k = 0; k < KMAX; ++k) p += uhat[k][o];
            s[o] = wave_sum(p) * (1.0f / (float)RR);
        }
        float n2 = 0.0f;
#pragma unroll
        for (int o = 0; o < OO; ++o) n2 += s[o] * s[o];
        const float scale = sqrtf(n2) / (1.0f + n2);
#pragma unroll
        for (int o = 0; o < OO; ++o) v[o] = s[o] * scale;
#pragma unroll
        for (int k = 0; k < KMAX; ++k) {
            float a = 0.0f;
#pragma unroll
            for (int o = 0; o < OO; ++o) a += uhat[k][o] * v[o];
            b_r[k] = a;
        }
    }

    // iterations 1 and 2
#pragma unroll
    for (int it = 1; it < 3; ++it) {
        float mloc = -INFINITY;
#pragma unroll
        for (int k = 0; k < KMAX; ++k) {
            const bool valid = (k < KMAX - 1) || (lane < 32);
            if (valid) mloc = fmaxf(mloc, b_r[k]);
        }
        const float m = wave_max(mloc);

        float zp = 0.0f;
        float sp[OO];
#pragma unroll
        for (int o = 0; o < OO; ++o) sp[o] = 0.0f;
#pragma unroll
        for (int k = 0; k < KMAX; ++k) {
            const bool valid = (k < KMAX - 1) || (lane < 32);
            const float e = valid ? __expf(b_r[k] - m) : 0.0f;
            zp += e;
#pragma unroll
            for (int o = 0; o < OO; ++o) sp[o] += e * uhat[k][o];
        }
        const float Z = wave_sum(zp);
        const float invZ = 1.0f / Z;

        float s[OO];
#pragma unroll
        for (int o = 0; o < OO; ++o) s[o] = wave_sum(sp[o]) * invZ;

        float n2 = 0.0f;
#pragma unroll
        for (int o = 0; o < OO; ++o) n2 += s[o] * s[o];
        const float scale = sqrtf(n2) / (1.0f + n2);
#pragma unroll
        for (int o = 0; o < OO; ++o) v[o] = s[o] * scale;

        if (it < 2) {
#pragma unroll
            for (int k = 0; k < KMAX; ++k) {
                float a = 0.0f;
#pragma unroll
                for (int o = 0; o < OO; ++o) a += uhat[k][o] * v[o];
                b_r[k] += a;
            }
        }
    }

    // ---- write out[b][j][o]; all lanes hold v after butterfly reductions ----
    float outv = 0.0f;
#pragma unroll
    for (int o = 0; o < OO; ++o)
        if (lane == o) outv = v[o];
    if (lane < OO) out[(b * JJ + j) * OO + lane] = outv;
}

extern "C" void kernel_launch(void* const* d_in, const int* in_sizes, int n_in,
                              void* d_out, int out_size, void* d_ws, size_t ws_size,
                              hipStream_t stream) {
    const float* u = (const float*)d_in[0];  // [128, 864, 4]
    const float* W = (const float*)d_in[1];  // [1, 166, 864, 8, 4]
    float* out = (float*)d_out;              // [128, 166, 8]

    const int grid = JJ * (BB / 4);  // 166 * 32 = 5312 blocks, 4 waves each
    digitcaps_kernel<<<grid, 256, 0, stream>>>(u, W, out);
}

// Round 4
// 213.220 us; speedup vs baseline: 2.0687x; 1.2151x over previous
//
#include <hip/hip_runtime.h>
#include <math.h>

// DigitCaps dynamic routing, MI355X. Round 3: occupancy push (fixed fp16 typedef).
// u[B=128, R=864, I=4] f32, W[1, J=166, R=864, O=8, I=4] f32 -> v[128,166,8] f32.
//
// Block = 256 threads = 4 waves sharing one j, 4 consecutive b.
// W[j] staged in 4 chunks of 256 routes (32.9 KB LDS, transposed+padded ->
// conflict-free b128 on both sides; verified 0 conflicts in round 1).
// u_hat stored as packed fp16 (56 VGPRs instead of 112); all accumulation in
// fp32. Routing logits are never stored: b_r = <u_hat[r], V> with V = sum of
// past v's (additive-update identity), recomputed on the fly. No softmax max
// pass (|b_r| <~ 25, exp safe in fp32, softmax shift-invariant).

#define BB 128
#define JJ 166
#define RR 864
#define OO 8
#define KMAX 14            // ceil(864/64); k=13 has only lanes 0..31 valid
#define RPAD4 257          // LDS row stride in float4 (256 routes + 1 pad)

typedef __fp16 h2 __attribute__((ext_vector_type(2)));

__device__ __forceinline__ float wave_sum(float v) {
#pragma unroll
    for (int m = 32; m >= 1; m >>= 1) v += __shfl_xor(v, m, 64);
    return v;
}

__global__ __launch_bounds__(256, 3) void digitcaps_kernel(
    const float* __restrict__ u, const float* __restrict__ W,
    float* __restrict__ out) {
    const int tid = threadIdx.x;
    const int lane = tid & 63;
    const int wave = tid >> 6;

    // 32 blocks per j; consecutive blocks share j for L2 locality.
    const int j = blockIdx.x >> 5;
    const int b = ((blockIdx.x & 31) << 2) + wave;

    const float4* __restrict__ u4 = (const float4*)u;  // [B][R]
    const float4* __restrict__ W4 = (const float4*)W;  // [J][R][O]

    __shared__ float4 wlds[OO * RPAD4];  // 32,896 B

    h2 uh[KMAX][4];  // u_hat packed fp16: [k][o-pair] -> 56 VGPRs

    // ---- stage W[j] in 4 chunks of 256 r; compute u_hat into fp16 regs ----
#pragma unroll
    for (int c = 0; c < 4; ++c) {
        __syncthreads();  // protect LDS reuse across chunks
        const int base_r = c << 8;                      // 0,256,512,768
        const int gbase = j * (RR * OO) + base_r * OO;  // float4 index
        const int iters = (c < 3) ? 8 : 3;              // (256|96)*8/256
#pragma unroll
        for (int i = 0; i < iters; ++i) {
            const int e = tid + (i << 8);
            const float4 w = W4[gbase + e];
            wlds[(e & 7) * RPAD4 + (e >> 3)] = w;  // transposed: [o][r_local]
        }
        __syncthreads();

        const int kk = (c < 3) ? 4 : 2;
#pragma unroll
        for (int kl = 0; kl < kk; ++kl) {
            const int k = (c << 2) + kl;
            const int rl = (kl << 6) + lane;
            const int r = base_r + rl;
            if (r < RR) {  // only k==13, lane>=32 fails
                const float4 uu = u4[b * RR + r];
                float d[OO];
#pragma unroll
                for (int o = 0; o < OO; ++o) {
                    const float4 ww = wlds[o * RPAD4 + rl];
                    d[o] = ww.x * uu.x + ww.y * uu.y + ww.z * uu.z + ww.w * uu.w;
                }
#pragma unroll
                for (int o2 = 0; o2 < 4; ++o2)
                    uh[k][o2] = __builtin_amdgcn_cvt_pkrtz(d[2 * o2], d[2 * o2 + 1]);
            } else {
#pragma unroll
                for (int o2 = 0; o2 < 4; ++o2) uh[k][o2] = (h2)(__fp16)0;
            }
        }
    }

    float V[OO];  // running sum of past v's (b_r = <uhat_r, V>)
    float v[OO];

    // ---- iteration 0: b=0 -> c uniform = 1/R ----
    {
        float acc[OO];
#pragma unroll
        for (int o = 0; o < OO; ++o) acc[o] = 0.0f;
#pragma unroll
        for (int k = 0; k < KMAX; ++k)
#pragma unroll
            for (int o2 = 0; o2 < 4; ++o2) {
                acc[2 * o2]     += (float)uh[k][o2].x;
                acc[2 * o2 + 1] += (float)uh[k][o2].y;
            }

        float s[OO];
#pragma unroll
        for (int o = 0; o < OO; ++o)
            s[o] = wave_sum(acc[o]) * (1.0f / (float)RR);

        float n2 = 0.0f;
#pragma unroll
        for (int o = 0; o < OO; ++o) n2 += s[o] * s[o];
        const float scale = sqrtf(n2) / (1.0f + n2);
#pragma unroll
        for (int o = 0; o < OO; ++o) { v[o] = s[o] * scale; V[o] = v[o]; }
    }

    // ---- iterations 1 and 2 ----
#pragma unroll
    for (int it = 1; it < 3; ++it) {
        float zp = 0.0f;
        float sp[OO];
#pragma unroll
        for (int o = 0; o < OO; ++o) sp[o] = 0.0f;

#pragma unroll
        for (int k = 0; k < KMAX; ++k) {
            float uf[OO];
#pragma unroll
            for (int o2 = 0; o2 < 4; ++o2) {
                uf[2 * o2]     = (float)uh[k][o2].x;
                uf[2 * o2 + 1] = (float)uh[k][o2].y;
            }
            float br = 0.0f;
#pragma unroll
            for (int o = 0; o < OO; ++o) br = fmaf(uf[o], V[o], br);
            // mask invalid routes (k==13, lane>=32): exp(0)=1 would pollute Z
            const float e = (k < KMAX - 1 || lane < 32) ? __expf(br) : 0.0f;
            zp += e;
#pragma unroll
            for (int o = 0; o < OO; ++o) sp[o] = fmaf(e, uf[o], sp[o]);
        }
        const float invZ = 1.0f / wave_sum(zp);

        float s[OO];
#pragma unroll
        for (int o = 0; o < OO; ++o) s[o] = wave_sum(sp[o]) * invZ;

        float n2 = 0.0f;
#pragma unroll
        for (int o = 0; o < OO; ++o) n2 += s[o] * s[o];
        const float scale = sqrtf(n2) / (1.0f + n2);
#pragma unroll
        for (int o = 0; o < OO; ++o) v[o] = s[o] * scale;

        if (it < 2) {
#pragma unroll
            for (int o = 0; o < OO; ++o) V[o] += v[o];
        }
    }

    // ---- write out[b][j][o]; v replicated across lanes after butterflies ----
    float outv = 0.0f;
#pragma unroll
    for (int o = 0; o < OO; ++o)
        if (lane == o) outv = v[o];
    if (lane < OO) out[(b * JJ + j) * OO + lane] = outv;
}

extern "C" void kernel_launch(void* const* d_in, const int* in_sizes, int n_in,
                              void* d_out, int out_size, void* d_ws, size_t ws_size,
                              hipStream_t stream) {
    const float* u = (const float*)d_in[0];  // [128, 864, 4]
    const float* W = (const float*)d_in[1];  // [1, 166, 864, 8, 4]
    float* out = (float*)d_out;              // [128, 166, 8]

    const int grid = JJ * (BB / 4);  // 5312 blocks, 4 waves each
    digitcaps_kernel<<<grid, 256, 0, stream>>>(u, W, out);
}